// Round 2
// baseline (661.457 us; speedup 1.0000x reference)
//
#include <hip/hip_runtime.h>
#include <cmath>

#define B_SZ  1024
#define NORB  128
#define NUP   32
#define HID   4096
#define NCORR (NORB * NUP)   // 4096

// ---------------------------------------------------------------------------
// Kernel A: h[b,:] = relu(b1 + sum_i W1[4*i + x[b,i], :])
// One block per sample, 256 threads, 16 hidden columns per thread.
// ---------------------------------------------------------------------------
__global__ __launch_bounds__(256) void k_hidden(const int* __restrict__ x,
                                                const float* __restrict__ W1,
                                                const float* __restrict__ b1,
                                                float* __restrict__ h) {
    int b = blockIdx.x, tid = threadIdx.x;
    __shared__ int sx[NORB];
    if (tid < NORB) sx[tid] = x[b * NORB + tid];
    __syncthreads();

    float acc[16];
#pragma unroll
    for (int u = 0; u < 16; ++u) acc[u] = b1[tid + 256 * u];

    for (int i = 0; i < NORB; ++i) {
        const float* row = W1 + (size_t)(4 * i + sx[i]) * HID;
#pragma unroll
        for (int u = 0; u < 16; ++u) acc[u] += row[tid + 256 * u];
    }

    float* hb = h + (size_t)b * HID;
#pragma unroll
    for (int u = 0; u < 16; ++u) hb[tid + 256 * u] = fmaxf(acc[u], 0.f);
}

// ---------------------------------------------------------------------------
// Kernel B: corr[1024,4096] = h[1024,4096] @ W2[4096,4096] + b2
// f32 tiled GEMM: BM=BN=64, BK=32, 256 threads, 4x4 microtile.
// As stored transposed [k][m] with pad 68 (16B-aligned float4 rows).
// ---------------------------------------------------------------------------
#define BM 64
#define BN 64
#define BK 32

__global__ __launch_bounds__(256) void k_gemm(const float* __restrict__ A,
                                              const float* __restrict__ Bm,
                                              const float* __restrict__ bias,
                                              float* __restrict__ C) {
    __shared__ float As[BK][68];   // [k][m], pad 68: 68*4=272 bytes, 16B aligned
    __shared__ float Bs[BK][BN];   // [k][n]

    int n0 = blockIdx.x * BN;
    int m0 = blockIdx.y * BM;
    int tid = threadIdx.x;
    int tm = tid >> 4;        // 0..15
    int tn = tid & 15;        // 0..15

    // staging coords
    int am = tid >> 3;        // 0..31 (+32)
    int ak = (tid & 7) * 4;   // 0,4,..,28
    int bk = tid >> 4;        // 0..15 (+16)
    int bn = (tid & 15) * 4;  // 0,4,..,60

    float acc[4][4] = {};

    for (int k0 = 0; k0 < HID; k0 += BK) {
#pragma unroll
        for (int t = 0; t < 2; ++t) {
            int m = am + 32 * t;
            float4 v = *(const float4*)(A + (size_t)(m0 + m) * HID + k0 + ak);
            As[ak + 0][m] = v.x; As[ak + 1][m] = v.y;
            As[ak + 2][m] = v.z; As[ak + 3][m] = v.w;
        }
#pragma unroll
        for (int t = 0; t < 2; ++t) {
            int k = bk + 16 * t;
            float4 v = *(const float4*)(Bm + (size_t)(k0 + k) * NCORR + n0 + bn);
            *(float4*)&Bs[k][bn] = v;
        }
        __syncthreads();

#pragma unroll
        for (int kk = 0; kk < BK; ++kk) {
            float4 a  = *(const float4*)&As[kk][tm * 4];
            float4 bv = *(const float4*)&Bs[kk][tn * 4];
            float av[4] = {a.x, a.y, a.z, a.w};
            float bb[4] = {bv.x, bv.y, bv.z, bv.w};
#pragma unroll
            for (int i = 0; i < 4; ++i)
#pragma unroll
                for (int j = 0; j < 4; ++j) acc[i][j] += av[i] * bb[j];
        }
        __syncthreads();
    }

#pragma unroll
    for (int i = 0; i < 4; ++i) {
        int m = m0 + tm * 4 + i;
        float4 o;
        o.x = acc[i][0] + bias[n0 + tn * 4 + 0];
        o.y = acc[i][1] + bias[n0 + tn * 4 + 1];
        o.z = acc[i][2] + bias[n0 + tn * 4 + 2];
        o.w = acc[i][3] + bias[n0 + tn * 4 + 3];
        *(float4*)(C + (size_t)m * NCORR + n0 + tn * 4) = o;
    }
}

// ---------------------------------------------------------------------------
// Kernel C: per sample — gather occupied orbitals, M = phi + d (32x32) per
// spin, LU with partial pivoting (one wave per matrix), write complex logdet.
// Output layout: PLANAR — out[b] = Re, out[imag_off + b] = Im (if imag_off>0).
// ---------------------------------------------------------------------------
__global__ __launch_bounds__(128) void k_det(const int* __restrict__ x,
                                             const float* __restrict__ orbitals,
                                             const float* __restrict__ corr,
                                             float* __restrict__ out,
                                             int imag_off) {
    int b = blockIdx.x, tid = threadIdx.x;
    __shared__ int sx[NORB];
    __shared__ int yup[NUP], ydn[NUP];
    __shared__ float M[2][NUP][NUP + 1];
    __shared__ float rlog[2];
    __shared__ int rneg[2];

    sx[tid] = x[b * NORB + tid];   // block = 128 = NORB threads
    __syncthreads();

    int occ = sx[tid];
    if (occ & 1) {
        int r = 0;
        for (int i = 0; i < tid; ++i) r += sx[i] & 1;
        yup[r] = tid;
    }
    if (occ & 2) {
        int r = 0;
        for (int i = 0; i < tid; ++i) r += (sx[i] >> 1) & 1;
        ydn[r] = tid;
    }
    __syncthreads();

    const float* cb = corr + (size_t)b * NCORR;
    for (int idx = tid; idx < 2 * NUP * NUP; idx += 128) {
        int s = idx >> 10;
        int i = (idx >> 5) & 31;
        int j = idx & 31;
        int r = s ? ydn[i] : yup[i];
        M[s][i][j] = orbitals[r * NUP + j] + cb[r * NUP + j];
    }
    __syncthreads();

    int wv = tid >> 6, lane = tid & 63;
    float (*Mm)[NUP + 1] = M[wv];
    float logdet = 0.f;
    int neg = 0;

    for (int k = 0; k < NUP; ++k) {
        // --- pivot search over rows k..31 of column k (wave64 reduce) ---
        float v = (lane >= k && lane < NUP) ? fabsf(Mm[lane][k]) : -1.f;
        int pi = lane;
#pragma unroll
        for (int off = 32; off > 0; off >>= 1) {
            float v2 = __shfl_down(v, off);
            int p2 = __shfl_down(pi, off);
            if (v2 > v) { v = v2; pi = p2; }
        }
        int p = __shfl(pi, 0);

        // --- row swap (per-lane column c: no cross-lane aliasing) ---
        if (p != k) {
            if (lane < NUP) {
                float t1 = Mm[k][lane];
                Mm[k][lane] = Mm[p][lane];
                Mm[p][lane] = t1;
            }
            neg ^= 1;
        }
        __syncthreads();

        float pv = Mm[k][k];
        logdet += logf(fabsf(pv));
        if (pv < 0.f) neg ^= 1;

        // --- rank-1 update rows k+1..31, 2 lanes per row (interleaved cols)
        int row = k + 1 + (lane & 31);
        int half = lane >> 5;
        if (row < NUP) {
            float f = Mm[row][k] / pv;
            for (int j = k + 1 + half; j < NUP; j += 2)
                Mm[row][j] -= f * Mm[k][j];
        }
        __syncthreads();
    }

    if (lane == 0) { rlog[wv] = logdet; rneg[wv] = neg; }
    __syncthreads();
    if (tid == 0) {
        out[b] = rlog[0] + rlog[1];
        if (imag_off > 0)
            out[imag_off + b] =
                (rneg[0] ^ rneg[1]) ? 3.14159265358979323846f : 0.f;
    }
}

// ---------------------------------------------------------------------------
extern "C" void kernel_launch(void* const* d_in, const int* in_sizes, int n_in,
                              void* d_out, int out_size, void* d_ws, size_t ws_size,
                              hipStream_t stream) {
    const int*   x        = (const int*)d_in[0];
    const float* orbitals = (const float*)d_in[1];
    const float* W1       = (const float*)d_in[2];
    const float* b1       = (const float*)d_in[3];
    const float* W2       = (const float*)d_in[4];
    const float* b2       = (const float*)d_in[5];
    float* out = (float*)d_out;

    float* h    = (float*)d_ws;                       // 1024*4096 f32 = 16 MB
    float* corr = h + (size_t)B_SZ * HID;             // 1024*4096 f32 = 16 MB

    k_hidden<<<B_SZ, 256, 0, stream>>>(x, W1, b1, h);

    dim3 g2(NCORR / BN, B_SZ / BM);                   // 64 x 16 = 1024 blocks
    k_gemm<<<g2, 256, 0, stream>>>(h, W2, b2, corr);

    // Planar complex layout: [Re(0..1023), Im(0..1023)] when out_size==2048;
    // real-only when out_size==1024.
    int imag_off = (out_size == 2 * B_SZ) ? B_SZ : 0;
    k_det<<<B_SZ, 128, 0, stream>>>(x, orbitals, corr, out, imag_off);
}

// Round 3
// 640.908 us; speedup vs baseline: 1.0321x; 1.0321x over previous
//
#include <hip/hip_runtime.h>
#include <cmath>

#define B_SZ  1024
#define NORB  128
#define NUP   32
#define HID   4096
#define NCORR (NORB * NUP)   // 4096

typedef short  bf16x8 __attribute__((ext_vector_type(8)));
typedef float  f32x4  __attribute__((ext_vector_type(4)));

__device__ __forceinline__ unsigned short f2bf_rne(float f) {
    unsigned int u = __float_as_uint(f);
    u += 0x7FFFu + ((u >> 16) & 1u);
    return (unsigned short)(u >> 16);
}

// ---------------------------------------------------------------------------
// Kernel A: h[b,:] = relu(b1 + sum_i W1[4*i + x[b,i], :]), emitted as
// split bf16: h_hi = bf16(h), h_lo = bf16(h - h_hi). Row-major [B][HID].
// ---------------------------------------------------------------------------
__global__ __launch_bounds__(256) void k_hidden(const int* __restrict__ x,
                                                const float* __restrict__ W1,
                                                const float* __restrict__ b1,
                                                unsigned short* __restrict__ h_hi,
                                                unsigned short* __restrict__ h_lo) {
    int b = blockIdx.x, tid = threadIdx.x;
    __shared__ int sx[NORB];
    if (tid < NORB) sx[tid] = x[b * NORB + tid];
    __syncthreads();

    float acc[16];
#pragma unroll
    for (int u = 0; u < 16; ++u) acc[u] = b1[tid + 256 * u];

    for (int i = 0; i < NORB; ++i) {
        const float* row = W1 + (size_t)(4 * i + sx[i]) * HID;
#pragma unroll
        for (int u = 0; u < 16; ++u) acc[u] += row[tid + 256 * u];
    }

    size_t base = (size_t)b * HID + tid;
#pragma unroll
    for (int u = 0; u < 16; ++u) {
        float v = fmaxf(acc[u], 0.f);
        unsigned short hi = f2bf_rne(v);
        float fhi = __uint_as_float((unsigned int)hi << 16);
        unsigned short lo = f2bf_rne(v - fhi);
        h_hi[base + 256 * u] = hi;
        h_lo[base + 256 * u] = lo;
    }
}

// f32 fallback variant (used only if workspace is too small for fast path)
__global__ __launch_bounds__(256) void k_hidden_f32(const int* __restrict__ x,
                                                    const float* __restrict__ W1,
                                                    const float* __restrict__ b1,
                                                    float* __restrict__ h) {
    int b = blockIdx.x, tid = threadIdx.x;
    __shared__ int sx[NORB];
    if (tid < NORB) sx[tid] = x[b * NORB + tid];
    __syncthreads();
    float acc[16];
#pragma unroll
    for (int u = 0; u < 16; ++u) acc[u] = b1[tid + 256 * u];
    for (int i = 0; i < NORB; ++i) {
        const float* row = W1 + (size_t)(4 * i + sx[i]) * HID;
#pragma unroll
        for (int u = 0; u < 16; ++u) acc[u] += row[tid + 256 * u];
    }
    float* hb = h + (size_t)b * HID;
#pragma unroll
    for (int u = 0; u < 16; ++u) hb[tid + 256 * u] = fmaxf(acc[u], 0.f);
}

// ---------------------------------------------------------------------------
// Kernel S: W2 [k][n] f32  ->  W2t_hi/W2t_lo [n][k] bf16 (split + transpose).
// 32x32 LDS tile, both sides coalesced.
// ---------------------------------------------------------------------------
__global__ __launch_bounds__(256) void k_split(const float* __restrict__ W2,
                                               unsigned short* __restrict__ Whi,
                                               unsigned short* __restrict__ Wlo) {
    __shared__ float tile[32][33];
    int n0 = blockIdx.x * 32, k0 = blockIdx.y * 32;
    int t = threadIdx.x;
    int c = t & 31, r4 = t >> 5;           // c: 0..31, r4: 0..7
#pragma unroll
    for (int i = 0; i < 4; ++i) {
        int r = r4 * 4 + i;
        tile[r][c] = W2[(size_t)(k0 + r) * NCORR + n0 + c];
    }
    __syncthreads();
#pragma unroll
    for (int i = 0; i < 4; ++i) {
        int n = r4 * 4 + i, k = c;
        float v = tile[k][n];
        unsigned short hi = f2bf_rne(v);
        float fhi = __uint_as_float((unsigned int)hi << 16);
        unsigned short lo = f2bf_rne(v - fhi);
        size_t o = (size_t)(n0 + n) * NCORR + k0 + k;
        Whi[o] = hi;
        Wlo[o] = lo;
    }
}

// ---------------------------------------------------------------------------
// Kernel B: corr = (h_hi+h_lo)@W2_hi + h_hi@W2_lo + b2 via bf16 MFMA, f32 acc.
// Tile: BM=64, BN=128, BK=32; 256 threads = 4 waves, each 64m x 32n.
// Fragment layouts (gfx950, verified):
//   A: lane holds A[m=lane&15][k=quad*8+j]   (LDS: [m][k], k-contig)
//   B: lane holds B[k=quad*8+j][n=lane&15]   (LDS: [n][k], k-contig)
//   D: reg r -> row=quad*4+r, col=lane&15
// ---------------------------------------------------------------------------
#define GBM 64
#define GBN 128
#define GBK 32
#define LPAD 40   // row stride in bf16 elems: 32 + 8 (16B-aligned, 2-way max)

__global__ __launch_bounds__(256) void k_gemm2(const unsigned short* __restrict__ Ah_g,
                                               const unsigned short* __restrict__ Al_g,
                                               const unsigned short* __restrict__ Bh_g,
                                               const unsigned short* __restrict__ Bl_g,
                                               const float* __restrict__ bias,
                                               float* __restrict__ C) {
    __shared__ unsigned short Ah[GBM][LPAD], Al[GBM][LPAD];
    __shared__ unsigned short Bh[GBN][LPAD], Bl[GBN][LPAD];

    int n0 = blockIdx.x * GBN;
    int m0 = blockIdx.y * GBM;
    int t = threadIdx.x;
    int w = t >> 6, lane = t & 63;
    int lm = lane & 15, kq = lane >> 4;    // frag row/col + k-quad
    int wn = w * 32;                        // wave n-offset within tile

    // staging coords
    int ma = t >> 2, ga = t & 3;           // A: one 16B group per thread
    int nb = t & 127, gb = t >> 7;         // B: two 16B groups per thread

    f32x4 acc[4][2] = {};

    for (int k0 = 0; k0 < HID; k0 += GBK) {
        // ---- global loads (issued before barrier for overlap) ----
        float4 vah = *(const float4*)(Ah_g + (size_t)(m0 + ma) * HID + k0 + ga * 8);
        float4 val = *(const float4*)(Al_g + (size_t)(m0 + ma) * HID + k0 + ga * 8);
        float4 vb[4];
#pragma unroll
        for (int s = 0; s < 2; ++s) {
            int g = gb + 2 * s;
            vb[2 * s]     = *(const float4*)(Bh_g + (size_t)(n0 + nb) * HID + k0 + g * 8);
            vb[2 * s + 1] = *(const float4*)(Bl_g + (size_t)(n0 + nb) * HID + k0 + g * 8);
        }

        __syncthreads();   // previous iteration's LDS reads complete
        *(float4*)&Ah[ma][ga * 8] = vah;
        *(float4*)&Al[ma][ga * 8] = val;
#pragma unroll
        for (int s = 0; s < 2; ++s) {
            int g = gb + 2 * s;
            *(float4*)&Bh[nb][g * 8] = vb[2 * s];
            *(float4*)&Bl[nb][g * 8] = vb[2 * s + 1];
        }
        __syncthreads();

        // ---- fragments + MFMA ----
        bf16x8 afh[4], afl[4];
#pragma unroll
        for (int fm = 0; fm < 4; ++fm) {
            afh[fm] = *(const bf16x8*)&Ah[fm * 16 + lm][kq * 8];
            afl[fm] = *(const bf16x8*)&Al[fm * 16 + lm][kq * 8];
        }
#pragma unroll
        for (int fn = 0; fn < 2; ++fn) {
            bf16x8 bfh = *(const bf16x8*)&Bh[wn + fn * 16 + lm][kq * 8];
            bf16x8 bfl = *(const bf16x8*)&Bl[wn + fn * 16 + lm][kq * 8];
#pragma unroll
            for (int fm = 0; fm < 4; ++fm) {
                acc[fm][fn] = __builtin_amdgcn_mfma_f32_16x16x32_bf16(afh[fm], bfh, acc[fm][fn], 0, 0, 0);
                acc[fm][fn] = __builtin_amdgcn_mfma_f32_16x16x32_bf16(afl[fm], bfh, acc[fm][fn], 0, 0, 0);
                acc[fm][fn] = __builtin_amdgcn_mfma_f32_16x16x32_bf16(afh[fm], bfl, acc[fm][fn], 0, 0, 0);
            }
        }
    }

    // ---- epilogue: bias + store ----
#pragma unroll
    for (int fm = 0; fm < 4; ++fm)
#pragma unroll
        for (int fn = 0; fn < 2; ++fn) {
            int n = n0 + wn + fn * 16 + lm;
            float bv = bias[n];
#pragma unroll
            for (int r = 0; r < 4; ++r) {
                int m = m0 + fm * 16 + kq * 4 + r;
                C[(size_t)m * NCORR + n] = acc[fm][fn][r] + bv;
            }
        }
}

// ---------------------------------------------------------------------------
// f32 fallback GEMM (round-2 kernel, unchanged)
// ---------------------------------------------------------------------------
#define BM 64
#define BN 64
#define BK 32
__global__ __launch_bounds__(256) void k_gemm(const float* __restrict__ A,
                                              const float* __restrict__ Bm,
                                              const float* __restrict__ bias,
                                              float* __restrict__ C) {
    __shared__ float As[BK][68];
    __shared__ float Bs[BK][BN];
    int n0 = blockIdx.x * BN, m0 = blockIdx.y * BM;
    int tid = threadIdx.x;
    int tm = tid >> 4, tn = tid & 15;
    int am = tid >> 3, ak = (tid & 7) * 4;
    int bk = tid >> 4, bn = (tid & 15) * 4;
    float acc[4][4] = {};
    for (int k0 = 0; k0 < HID; k0 += BK) {
#pragma unroll
        for (int s = 0; s < 2; ++s) {
            int m = am + 32 * s;
            float4 v = *(const float4*)(A + (size_t)(m0 + m) * HID + k0 + ak);
            As[ak + 0][m] = v.x; As[ak + 1][m] = v.y;
            As[ak + 2][m] = v.z; As[ak + 3][m] = v.w;
        }
#pragma unroll
        for (int s = 0; s < 2; ++s) {
            int k = bk + 16 * s;
            float4 v = *(const float4*)(Bm + (size_t)(k0 + k) * NCORR + n0 + bn);
            *(float4*)&Bs[k][bn] = v;
        }
        __syncthreads();
#pragma unroll
        for (int kk = 0; kk < BK; ++kk) {
            float4 a = *(const float4*)&As[kk][tm * 4];
            float4 bv = *(const float4*)&Bs[kk][tn * 4];
            float av[4] = {a.x, a.y, a.z, a.w};
            float bb[4] = {bv.x, bv.y, bv.z, bv.w};
#pragma unroll
            for (int i = 0; i < 4; ++i)
#pragma unroll
                for (int j = 0; j < 4; ++j) acc[i][j] += av[i] * bb[j];
        }
        __syncthreads();
    }
#pragma unroll
    for (int i = 0; i < 4; ++i) {
        int m = m0 + tm * 4 + i;
        float4 o;
        o.x = acc[i][0] + bias[n0 + tn * 4 + 0];
        o.y = acc[i][1] + bias[n0 + tn * 4 + 1];
        o.z = acc[i][2] + bias[n0 + tn * 4 + 2];
        o.w = acc[i][3] + bias[n0 + tn * 4 + 3];
        *(float4*)(C + (size_t)m * NCORR + n0 + tn * 4) = o;
    }
}

// ---------------------------------------------------------------------------
// Kernel C: gather + 32x32 LU (partial pivoting) per spin, planar complex out.
// ---------------------------------------------------------------------------
__global__ __launch_bounds__(128) void k_det(const int* __restrict__ x,
                                             const float* __restrict__ orbitals,
                                             const float* __restrict__ corr,
                                             float* __restrict__ out,
                                             int imag_off) {
    int b = blockIdx.x, tid = threadIdx.x;
    __shared__ int sx[NORB];
    __shared__ int yup[NUP], ydn[NUP];
    __shared__ float M[2][NUP][NUP + 1];
    __shared__ float rlog[2];
    __shared__ int rneg[2];

    sx[tid] = x[b * NORB + tid];
    __syncthreads();

    int occ = sx[tid];
    if (occ & 1) {
        int r = 0;
        for (int i = 0; i < tid; ++i) r += sx[i] & 1;
        yup[r] = tid;
    }
    if (occ & 2) {
        int r = 0;
        for (int i = 0; i < tid; ++i) r += (sx[i] >> 1) & 1;
        ydn[r] = tid;
    }
    __syncthreads();

    const float* cb = corr + (size_t)b * NCORR;
    for (int idx = tid; idx < 2 * NUP * NUP; idx += 128) {
        int s = idx >> 10;
        int i = (idx >> 5) & 31;
        int j = idx & 31;
        int r = s ? ydn[i] : yup[i];
        M[s][i][j] = orbitals[r * NUP + j] + cb[r * NUP + j];
    }
    __syncthreads();

    int wv = tid >> 6, lane = tid & 63;
    float (*Mm)[NUP + 1] = M[wv];
    float logdet = 0.f;
    int neg = 0;

    for (int k = 0; k < NUP; ++k) {
        float v = (lane >= k && lane < NUP) ? fabsf(Mm[lane][k]) : -1.f;
        int pi = lane;
#pragma unroll
        for (int off = 32; off > 0; off >>= 1) {
            float v2 = __shfl_down(v, off);
            int p2 = __shfl_down(pi, off);
            if (v2 > v) { v = v2; pi = p2; }
        }
        int p = __shfl(pi, 0);

        if (p != k) {
            if (lane < NUP) {
                float t1 = Mm[k][lane];
                Mm[k][lane] = Mm[p][lane];
                Mm[p][lane] = t1;
            }
            neg ^= 1;
        }
        __syncthreads();

        float pv = Mm[k][k];
        logdet += logf(fabsf(pv));
        if (pv < 0.f) neg ^= 1;

        int row = k + 1 + (lane & 31);
        int half = lane >> 5;
        if (row < NUP) {
            float f = Mm[row][k] / pv;
            for (int j = k + 1 + half; j < NUP; j += 2)
                Mm[row][j] -= f * Mm[k][j];
        }
        __syncthreads();
    }

    if (lane == 0) { rlog[wv] = logdet; rneg[wv] = neg; }
    __syncthreads();
    if (tid == 0) {
        out[b] = rlog[0] + rlog[1];
        if (imag_off > 0)
            out[imag_off + b] =
                (rneg[0] ^ rneg[1]) ? 3.14159265358979323846f : 0.f;
    }
}

// ---------------------------------------------------------------------------
extern "C" void kernel_launch(void* const* d_in, const int* in_sizes, int n_in,
                              void* d_out, int out_size, void* d_ws, size_t ws_size,
                              hipStream_t stream) {
    const int*   x        = (const int*)d_in[0];
    const float* orbitals = (const float*)d_in[1];
    const float* W1       = (const float*)d_in[2];
    const float* b1       = (const float*)d_in[3];
    const float* W2       = (const float*)d_in[4];
    const float* b2       = (const float*)d_in[5];
    float* out = (float*)d_out;
    int imag_off = (out_size == 2 * B_SZ) ? B_SZ : 0;

    const size_t need = (size_t)96 * 1024 * 1024;
    if (ws_size >= need) {
        // fast path: split-bf16 MFMA GEMM
        unsigned short* h_hi = (unsigned short*)d_ws;                       //  8 MB
        unsigned short* h_lo = h_hi + (size_t)B_SZ * HID;                   //  8 MB
        unsigned short* Whi  = h_lo + (size_t)B_SZ * HID;                   // 32 MB
        unsigned short* Wlo  = Whi + (size_t)HID * NCORR;                   // 32 MB
        float*          corr = (float*)(Wlo + (size_t)HID * NCORR);        // 16 MB

        k_split<<<dim3(NCORR / 32, HID / 32), 256, 0, stream>>>(W2, Whi, Wlo);
        k_hidden<<<B_SZ, 256, 0, stream>>>(x, W1, b1, h_hi, h_lo);
        dim3 g2(NCORR / GBN, B_SZ / GBM);   // 32 x 16 = 512 blocks
        k_gemm2<<<g2, 256, 0, stream>>>(h_hi, h_lo, Whi, Wlo, b2, corr);
        k_det<<<B_SZ, 128, 0, stream>>>(x, orbitals, corr, out, imag_off);
    } else {
        // fallback: f32 pipeline (round-2)
        float* h    = (float*)d_ws;
        float* corr = h + (size_t)B_SZ * HID;
        k_hidden_f32<<<B_SZ, 256, 0, stream>>>(x, W1, b1, h);
        dim3 g2(NCORR / BN, B_SZ / BM);
        k_gemm<<<g2, 256, 0, stream>>>(h, W2, b2, corr);
        k_det<<<B_SZ, 128, 0, stream>>>(x, orbitals, corr, out, imag_off);
    }
}

// Round 4
// 342.161 us; speedup vs baseline: 1.9332x; 1.8731x over previous
//
#include <hip/hip_runtime.h>
#include <cmath>

#define B_SZ  1024
#define NORB  128
#define NUP   32
#define HID   4096
#define NCORR (NORB * NUP)   // 4096

typedef short  bf16x8 __attribute__((ext_vector_type(8)));
typedef float  f32x4  __attribute__((ext_vector_type(4)));

__device__ __forceinline__ unsigned short f2bf_rne(float f) {
    unsigned int u = __float_as_uint(f);
    u += 0x7FFFu + ((u >> 16) & 1u);
    return (unsigned short)(u >> 16);
}

// ---------------------------------------------------------------------------
// Kernel A: h[b,:] = relu(b1 + sum_i W1[4*i + x[b,i], :]), emitted as
// split bf16: h_hi = bf16(h), h_lo = bf16(h - h_hi). Row-major [B][HID].
// ---------------------------------------------------------------------------
__global__ __launch_bounds__(256) void k_hidden(const int* __restrict__ x,
                                                const float* __restrict__ W1,
                                                const float* __restrict__ b1,
                                                unsigned short* __restrict__ h_hi,
                                                unsigned short* __restrict__ h_lo) {
    int b = blockIdx.x, tid = threadIdx.x;
    __shared__ int sx[NORB];
    if (tid < NORB) sx[tid] = x[b * NORB + tid];
    __syncthreads();

    float acc[16];
#pragma unroll
    for (int u = 0; u < 16; ++u) acc[u] = b1[tid + 256 * u];

    for (int i = 0; i < NORB; ++i) {
        const float* row = W1 + (size_t)(4 * i + sx[i]) * HID;
#pragma unroll
        for (int u = 0; u < 16; ++u) acc[u] += row[tid + 256 * u];
    }

    size_t base = (size_t)b * HID + tid;
#pragma unroll
    for (int u = 0; u < 16; ++u) {
        float v = fmaxf(acc[u], 0.f);
        unsigned short hi = f2bf_rne(v);
        float fhi = __uint_as_float((unsigned int)hi << 16);
        unsigned short lo = f2bf_rne(v - fhi);
        h_hi[base + 256 * u] = hi;
        h_lo[base + 256 * u] = lo;
    }
}

// f32 fallback variant
__global__ __launch_bounds__(256) void k_hidden_f32(const int* __restrict__ x,
                                                    const float* __restrict__ W1,
                                                    const float* __restrict__ b1,
                                                    float* __restrict__ h) {
    int b = blockIdx.x, tid = threadIdx.x;
    __shared__ int sx[NORB];
    if (tid < NORB) sx[tid] = x[b * NORB + tid];
    __syncthreads();
    float acc[16];
#pragma unroll
    for (int u = 0; u < 16; ++u) acc[u] = b1[tid + 256 * u];
    for (int i = 0; i < NORB; ++i) {
        const float* row = W1 + (size_t)(4 * i + sx[i]) * HID;
#pragma unroll
        for (int u = 0; u < 16; ++u) acc[u] += row[tid + 256 * u];
    }
    float* hb = h + (size_t)b * HID;
#pragma unroll
    for (int u = 0; u < 16; ++u) hb[tid + 256 * u] = fmaxf(acc[u], 0.f);
}

// ---------------------------------------------------------------------------
// Kernel S: W2 [k][n] f32 -> B_pack hi/lo bf16 in MFMA B-FRAGMENT ORDER:
//   flat = ((nt*128 + kt)*64 + lane)*8 + j
//   where nt=n>>4, kt=k>>5, lane=((k>>3)&3)*16 + (n&15), j=k&7.
// A wave in k_gemm3 then loads one fragment as 64 lanes x 16B contiguous.
// Block: 64 k x 32 n tile via LDS transpose; reads & writes coalesced.
// ---------------------------------------------------------------------------
__global__ __launch_bounds__(256) void k_split(const float* __restrict__ W2,
                                               unsigned short* __restrict__ Bph,
                                               unsigned short* __restrict__ Bpl) {
    __shared__ float tile[64][33];
    int n0 = blockIdx.x * 32, k0 = blockIdx.y * 64;
    int t = threadIdx.x;
    int nl = t & 31, kg = t >> 5;          // nl: 0..31, kg: 0..7
#pragma unroll
    for (int i = 0; i < 8; ++i) {
        int kl = kg + i * 8;
        tile[kl][nl] = W2[(size_t)(k0 + kl) * NCORR + n0 + nl];
    }
    __syncthreads();

    // one 8-element k-chunk per thread: k8 = kg, n = nl
    int nt = (n0 + nl) >> 4;
    int kt = (k0 >> 5) + (kg >> 2);
    int lane_o = (kg & 3) * 16 + (nl & 15);
    size_t o = (((size_t)nt * 128 + kt) * 64 + lane_o) * 8;

    unsigned short hi8[8], lo8[8];
#pragma unroll
    for (int j = 0; j < 8; ++j) {
        float v = tile[kg * 8 + j][nl];
        unsigned short hi = f2bf_rne(v);
        float fhi = __uint_as_float((unsigned int)hi << 16);
        hi8[j] = hi;
        lo8[j] = f2bf_rne(v - fhi);
    }
    *(bf16x8*)(Bph + o) = *(bf16x8*)hi8;
    *(bf16x8*)(Bpl + o) = *(bf16x8*)lo8;
}

// ---------------------------------------------------------------------------
// Kernel B: corr = (h_hi+h_lo)@W2_hi + h_hi@W2_lo + b2, bf16 MFMA, f32 acc.
// Tile: BM=64, BN=128, BK=32; 4 waves, each 64m x 32n.
//  - A staged in LDS (shared by all 4 waves), register-prefetched 1 iter ahead
//  - B loaded global->VGPR directly from fragment-packed layout (no LDS)
// Fragment layouts verified end-to-end in round 3 (absmax 0):
//   A: lane holds A[m=lane&15][k=(lane>>4)*8+j]
//   B: lane holds B[k=(lane>>4)*8+j][n=lane&15]
//   D: reg r -> row=(lane>>4)*4+r, col=lane&15
// ---------------------------------------------------------------------------
#define GBM 64
#define GBN 128
#define LPAD 40   // LDS row stride (bf16): 32 + 8, 16B aligned

__global__ __launch_bounds__(256, 3) void k_gemm3(const unsigned short* __restrict__ Ah_g,
                                                  const unsigned short* __restrict__ Al_g,
                                                  const unsigned short* __restrict__ Bh_g,
                                                  const unsigned short* __restrict__ Bl_g,
                                                  const float* __restrict__ bias,
                                                  float* __restrict__ C) {
    __shared__ unsigned short Ah[GBM][LPAD], Al[GBM][LPAD];

    int n0 = blockIdx.x * GBN;
    int m0 = blockIdx.y * GBM;
    int t = threadIdx.x;
    int w = t >> 6, lane = t & 63;
    int lm = lane & 15, kq = lane >> 4;
    int wn = w * 32;

    // A staging: one float4 (8 bf16) per thread per array per iter
    int ma = t >> 2, ga = t & 3;
    const unsigned short* agh = Ah_g + (size_t)(m0 + ma) * HID + ga * 8;
    const unsigned short* agl = Al_g + (size_t)(m0 + ma) * HID + ga * 8;

    // B fragment pointers: frag (fn,kt) at + fn*65536 + kt*512 elems
    size_t nt0 = (size_t)((n0 + wn) >> 4);
    const unsigned short* bph = Bh_g + nt0 * 65536 + (size_t)lane * 8;
    const unsigned short* bpl = Bl_g + nt0 * 65536 + (size_t)lane * 8;

    f32x4 acc[4][2] = {};

    // prologue: A(0) into registers
    float4 vah = *(const float4*)(agh);
    float4 val = *(const float4*)(agl);

    for (int kt = 0; kt < 128; ++kt) {
        if (kt) __syncthreads();           // prior iter's LDS reads complete

        // B fragments for THIS iter: global->reg, consumed after ~2 barriers
        bf16x8 cbh0 = *(const bf16x8*)(bph + (size_t)kt * 512);
        bf16x8 cbh1 = *(const bf16x8*)(bph + 65536u + (size_t)kt * 512);
        bf16x8 cbl0 = *(const bf16x8*)(bpl + (size_t)kt * 512);
        bf16x8 cbl1 = *(const bf16x8*)(bpl + 65536u + (size_t)kt * 512);

        // stage A(kt) (registers loaded one iter ago)
        *(float4*)&Ah[ma][ga * 8] = vah;
        *(float4*)&Al[ma][ga * 8] = val;
        __syncthreads();

        // prefetch A(kt+1): a full iteration of slack before use
        if (kt + 1 < 128) {
            vah = *(const float4*)(agh + (kt + 1) * 32);
            val = *(const float4*)(agl + (kt + 1) * 32);
        }

        // A fragments from LDS
        bf16x8 afh[4], afl[4];
#pragma unroll
        for (int fm = 0; fm < 4; ++fm) {
            afh[fm] = *(const bf16x8*)&Ah[fm * 16 + lm][kq * 8];
            afl[fm] = *(const bf16x8*)&Al[fm * 16 + lm][kq * 8];
        }

#pragma unroll
        for (int fm = 0; fm < 4; ++fm) {
            acc[fm][0] = __builtin_amdgcn_mfma_f32_16x16x32_bf16(afh[fm], cbh0, acc[fm][0], 0, 0, 0);
            acc[fm][0] = __builtin_amdgcn_mfma_f32_16x16x32_bf16(afl[fm], cbh0, acc[fm][0], 0, 0, 0);
            acc[fm][0] = __builtin_amdgcn_mfma_f32_16x16x32_bf16(afh[fm], cbl0, acc[fm][0], 0, 0, 0);
            acc[fm][1] = __builtin_amdgcn_mfma_f32_16x16x32_bf16(afh[fm], cbh1, acc[fm][1], 0, 0, 0);
            acc[fm][1] = __builtin_amdgcn_mfma_f32_16x16x32_bf16(afl[fm], cbh1, acc[fm][1], 0, 0, 0);
            acc[fm][1] = __builtin_amdgcn_mfma_f32_16x16x32_bf16(afh[fm], cbl1, acc[fm][1], 0, 0, 0);
        }
    }

    // epilogue: bias + store
#pragma unroll
    for (int fm = 0; fm < 4; ++fm)
#pragma unroll
        for (int fn = 0; fn < 2; ++fn) {
            int n = n0 + wn + fn * 16 + lm;
            float bv = bias[n];
#pragma unroll
            for (int r = 0; r < 4; ++r) {
                int m = m0 + fm * 16 + kq * 4 + r;
                C[(size_t)m * NCORR + n] = acc[fm][fn][r] + bv;
            }
        }
}

// ---------------------------------------------------------------------------
// f32 fallback GEMM (round-2 kernel, unchanged)
// ---------------------------------------------------------------------------
#define BM 64
#define BN 64
#define BK 32
__global__ __launch_bounds__(256) void k_gemm(const float* __restrict__ A,
                                              const float* __restrict__ Bm,
                                              const float* __restrict__ bias,
                                              float* __restrict__ C) {
    __shared__ float As[BK][68];
    __shared__ float Bs[BK][BN];
    int n0 = blockIdx.x * BN, m0 = blockIdx.y * BM;
    int tid = threadIdx.x;
    int tm = tid >> 4, tn = tid & 15;
    int am = tid >> 3, ak = (tid & 7) * 4;
    int bk = tid >> 4, bn = (tid & 15) * 4;
    float acc[4][4] = {};
    for (int k0 = 0; k0 < HID; k0 += BK) {
#pragma unroll
        for (int s = 0; s < 2; ++s) {
            int m = am + 32 * s;
            float4 v = *(const float4*)(A + (size_t)(m0 + m) * HID + k0 + ak);
            As[ak + 0][m] = v.x; As[ak + 1][m] = v.y;
            As[ak + 2][m] = v.z; As[ak + 3][m] = v.w;
        }
#pragma unroll
        for (int s = 0; s < 2; ++s) {
            int k = bk + 16 * s;
            float4 v = *(const float4*)(Bm + (size_t)(k0 + k) * NCORR + n0 + bn);
            *(float4*)&Bs[k][bn] = v;
        }
        __syncthreads();
#pragma unroll
        for (int kk = 0; kk < BK; ++kk) {
            float4 a = *(const float4*)&As[kk][tm * 4];
            float4 bv = *(const float4*)&Bs[kk][tn * 4];
            float av[4] = {a.x, a.y, a.z, a.w};
            float bb[4] = {bv.x, bv.y, bv.z, bv.w};
#pragma unroll
            for (int i = 0; i < 4; ++i)
#pragma unroll
                for (int j = 0; j < 4; ++j) acc[i][j] += av[i] * bb[j];
        }
        __syncthreads();
    }
#pragma unroll
    for (int i = 0; i < 4; ++i) {
        int m = m0 + tm * 4 + i;
        float4 o;
        o.x = acc[i][0] + bias[n0 + tn * 4 + 0];
        o.y = acc[i][1] + bias[n0 + tn * 4 + 1];
        o.z = acc[i][2] + bias[n0 + tn * 4 + 2];
        o.w = acc[i][3] + bias[n0 + tn * 4 + 3];
        *(float4*)(C + (size_t)m * NCORR + n0 + tn * 4) = o;
    }
}

// ---------------------------------------------------------------------------
// Kernel C: gather + 32x32 LU (partial pivoting) per spin, planar complex out.
// ---------------------------------------------------------------------------
__global__ __launch_bounds__(128) void k_det(const int* __restrict__ x,
                                             const float* __restrict__ orbitals,
                                             const float* __restrict__ corr,
                                             float* __restrict__ out,
                                             int imag_off) {
    int b = blockIdx.x, tid = threadIdx.x;
    __shared__ int sx[NORB];
    __shared__ int yup[NUP], ydn[NUP];
    __shared__ float M[2][NUP][NUP + 1];
    __shared__ float rlog[2];
    __shared__ int rneg[2];

    sx[tid] = x[b * NORB + tid];
    __syncthreads();

    int occ = sx[tid];
    if (occ & 1) {
        int r = 0;
        for (int i = 0; i < tid; ++i) r += sx[i] & 1;
        yup[r] = tid;
    }
    if (occ & 2) {
        int r = 0;
        for (int i = 0; i < tid; ++i) r += (sx[i] >> 1) & 1;
        ydn[r] = tid;
    }
    __syncthreads();

    const float* cb = corr + (size_t)b * NCORR;
    for (int idx = tid; idx < 2 * NUP * NUP; idx += 128) {
        int s = idx >> 10;
        int i = (idx >> 5) & 31;
        int j = idx & 31;
        int r = s ? ydn[i] : yup[i];
        M[s][i][j] = orbitals[r * NUP + j] + cb[r * NUP + j];
    }
    __syncthreads();

    int wv = tid >> 6, lane = tid & 63;
    float (*Mm)[NUP + 1] = M[wv];
    float logdet = 0.f;
    int neg = 0;

    for (int k = 0; k < NUP; ++k) {
        float v = (lane >= k && lane < NUP) ? fabsf(Mm[lane][k]) : -1.f;
        int pi = lane;
#pragma unroll
        for (int off = 32; off > 0; off >>= 1) {
            float v2 = __shfl_down(v, off);
            int p2 = __shfl_down(pi, off);
            if (v2 > v) { v = v2; pi = p2; }
        }
        int p = __shfl(pi, 0);

        if (p != k) {
            if (lane < NUP) {
                float t1 = Mm[k][lane];
                Mm[k][lane] = Mm[p][lane];
                Mm[p][lane] = t1;
            }
            neg ^= 1;
        }
        __syncthreads();

        float pv = Mm[k][k];
        logdet += logf(fabsf(pv));
        if (pv < 0.f) neg ^= 1;

        int row = k + 1 + (lane & 31);
        int half = lane >> 5;
        if (row < NUP) {
            float f = Mm[row][k] / pv;
            for (int j = k + 1 + half; j < NUP; j += 2)
                Mm[row][j] -= f * Mm[k][j];
        }
        __syncthreads();
    }

    if (lane == 0) { rlog[wv] = logdet; rneg[wv] = neg; }
    __syncthreads();
    if (tid == 0) {
        out[b] = rlog[0] + rlog[1];
        if (imag_off > 0)
            out[imag_off + b] =
                (rneg[0] ^ rneg[1]) ? 3.14159265358979323846f : 0.f;
    }
}

// ---------------------------------------------------------------------------
extern "C" void kernel_launch(void* const* d_in, const int* in_sizes, int n_in,
                              void* d_out, int out_size, void* d_ws, size_t ws_size,
                              hipStream_t stream) {
    const int*   x        = (const int*)d_in[0];
    const float* orbitals = (const float*)d_in[1];
    const float* W1       = (const float*)d_in[2];
    const float* b1       = (const float*)d_in[3];
    const float* W2       = (const float*)d_in[4];
    const float* b2       = (const float*)d_in[5];
    float* out = (float*)d_out;
    int imag_off = (out_size == 2 * B_SZ) ? B_SZ : 0;

    const size_t need = (size_t)96 * 1024 * 1024;
    if (ws_size >= need) {
        unsigned short* h_hi = (unsigned short*)d_ws;                    //  8 MB
        unsigned short* h_lo = h_hi + (size_t)B_SZ * HID;                //  8 MB
        unsigned short* Bph  = h_lo + (size_t)B_SZ * HID;                // 32 MB
        unsigned short* Bpl  = Bph + (size_t)HID * NCORR;                // 32 MB
        float*          corr = (float*)(Bpl + (size_t)HID * NCORR);     // 16 MB

        k_split<<<dim3(NCORR / 32, HID / 64), 256, 0, stream>>>(W2, Bph, Bpl);
        k_hidden<<<B_SZ, 256, 0, stream>>>(x, W1, b1, h_hi, h_lo);
        dim3 g2(NCORR / GBN, B_SZ / GBM);   // 32 x 16 = 512 blocks
        k_gemm3<<<g2, 256, 0, stream>>>(h_hi, h_lo, Bph, Bpl, b2, corr);
        k_det<<<B_SZ, 128, 0, stream>>>(x, orbitals, corr, out, imag_off);
    } else {
        float* h    = (float*)d_ws;
        float* corr = h + (size_t)B_SZ * HID;
        k_hidden_f32<<<B_SZ, 256, 0, stream>>>(x, W1, b1, h);
        dim3 g2(NCORR / BN, B_SZ / BM);
        k_gemm<<<g2, 256, 0, stream>>>(h, W2, b2, corr);
        k_det<<<B_SZ, 128, 0, stream>>>(x, orbitals, corr, out, imag_off);
    }
}

// Round 5
// 269.892 us; speedup vs baseline: 2.4508x; 1.2678x over previous
//
#include <hip/hip_runtime.h>
#include <cmath>

#define B_SZ  1024
#define NORB  128
#define NUP   32
#define HID   4096
#define NCORR (NORB * NUP)   // 4096
#define K1    (4 * NORB)     // 512, one-hot GEMM K-dim

typedef short  bf16x8 __attribute__((ext_vector_type(8)));
typedef float  f32x4  __attribute__((ext_vector_type(4)));

__device__ __forceinline__ unsigned short f2bf_rne(float f) {
    unsigned int u = __float_as_uint(f);
    u += 0x7FFFu + ((u >> 16) & 1u);
    return (unsigned short)(u >> 16);
}

// ---------------------------------------------------------------------------
// k_packx: x [1024][128] int32 (codes 0..3) -> xp [1024][8] dwords, 2b/orbital.
// ---------------------------------------------------------------------------
__global__ __launch_bounds__(256) void k_packx(const int* __restrict__ x,
                                               unsigned int* __restrict__ xp) {
    int t = threadIdx.x;
    int row = blockIdx.x * 32 + (t >> 3);
    int d = t & 7;
    const int* src = x + row * NORB + d * 16;
    unsigned int dw = 0;
#pragma unroll
    for (int b = 0; b < 16; ++b) dw |= ((unsigned int)(src[b] & 3)) << (2 * b);
    xp[row * 8 + d] = dw;
}

// ---------------------------------------------------------------------------
// k_splitW: W [rows][4096] f32 -> hi/lo bf16 in MFMA B-FRAGMENT ORDER:
//   flat = ((nt*ktTot + kt)*64 + lane)*8 + j
//   nt=n>>4, kt=k>>5, lane=((k>>3)&3)*16 + (n&15), j=k&7.
// Used for W2 (ktTot=128) and W1 (ktTot=16). Tile 64k x 32n via LDS.
// ---------------------------------------------------------------------------
__global__ __launch_bounds__(256) void k_splitW(const float* __restrict__ W,
                                                unsigned short* __restrict__ Bph,
                                                unsigned short* __restrict__ Bpl,
                                                int ktTot) {
    __shared__ float tile[64][33];
    int n0 = blockIdx.x * 32, k0 = blockIdx.y * 64;
    int t = threadIdx.x;
    int nl = t & 31, kg = t >> 5;          // nl: 0..31, kg: 0..7
#pragma unroll
    for (int i = 0; i < 8; ++i) {
        int kl = kg + i * 8;
        tile[kl][nl] = W[(size_t)(k0 + kl) * 4096 + n0 + nl];
    }
    __syncthreads();

    int nt = (n0 + nl) >> 4;
    int kt = (k0 >> 5) + (kg >> 2);
    int lane_o = (kg & 3) * 16 + (nl & 15);
    size_t o = (((size_t)nt * ktTot + kt) * 64 + lane_o) * 8;

    unsigned short hi8[8], lo8[8];
#pragma unroll
    for (int j = 0; j < 8; ++j) {
        float v = tile[kg * 8 + j][nl];
        unsigned short hi = f2bf_rne(v);
        float fhi = __uint_as_float((unsigned int)hi << 16);
        hi8[j] = hi;
        lo8[j] = f2bf_rne(v - fhi);
    }
    *(bf16x8*)(Bph + o) = *(bf16x8*)hi8;
    *(bf16x8*)(Bpl + o) = *(bf16x8*)lo8;
}

// ---------------------------------------------------------------------------
// k_hidden2: h = relu(one_hot(x) @ (W1hi + W1lo) + b1), split-bf16 out.
// M=1024, K=512, N=4096. Tile 64m x 128n, 4 waves each 64m x 32n.
// A generated in-register from 2-bit packed x (exact bf16 one-hot);
// B global->VGPR from fragment-packed W1 (prefetched 1 kt ahead);
// NO barriers in the K-loop (sxp is read-only after staging).
// ---------------------------------------------------------------------------
__global__ __launch_bounds__(256) void k_hidden2(const unsigned int* __restrict__ xp,
                                                 const unsigned short* __restrict__ Bph,
                                                 const unsigned short* __restrict__ Bpl,
                                                 const float* __restrict__ b1,
                                                 unsigned short* __restrict__ h_hi,
                                                 unsigned short* __restrict__ h_lo) {
    __shared__ unsigned int sxp[64][8];   // packed codes for the m-tile (2 KB)

    int n0 = blockIdx.x * 128;
    int m0 = blockIdx.y * 64;
    int t = threadIdx.x;
    int w = t >> 6, lane = t & 63;
    int lm = lane & 15, kq = lane >> 4;
    int wn = w * 32;

    // stage packed x rows (coalesced, 2 dwords/thread)
#pragma unroll
    for (int i = 0; i < 2; ++i) {
        int idx = t + 256 * i;
        sxp[idx >> 3][idx & 7] = xp[(m0 + (idx >> 3)) * 8 + (idx & 7)];
    }
    __syncthreads();

    // B fragment pointers: frag (fn, kt) at + fn*(16*512) + kt*512 elems
    size_t nt0 = (size_t)((n0 + wn) >> 4);
    const unsigned short* bph = Bph + nt0 * (16 * 512) + (size_t)lane * 8;
    const unsigned short* bpl = Bpl + nt0 * (16 * 512) + (size_t)lane * 8;

    f32x4 acc[4][2] = {};

    // prologue: B(kt=0)
    bf16x8 nbh0 = *(const bf16x8*)(bph);
    bf16x8 nbh1 = *(const bf16x8*)(bph + 16 * 512);
    bf16x8 nbl0 = *(const bf16x8*)(bpl);
    bf16x8 nbl1 = *(const bf16x8*)(bpl + 16 * 512);

    for (int kt = 0; kt < 16; ++kt) {
        bf16x8 bh0 = nbh0, bh1 = nbh1, bl0 = nbl0, bl1 = nbl1;
        if (kt + 1 < 16) {
            nbh0 = *(const bf16x8*)(bph + (kt + 1) * 512);
            nbh1 = *(const bf16x8*)(bph + 16 * 512 + (kt + 1) * 512);
            nbl0 = *(const bf16x8*)(bpl + (kt + 1) * 512);
            nbl1 = *(const bf16x8*)(bpl + 16 * 512 + (kt + 1) * 512);
        }

        // A fragments: orbitals i0 = kt*8 + kq*2, i1 = i0+1 (same dword)
        int i0 = kt * 8 + kq * 2;
        int dwIdx = i0 >> 4;
        int sh = (i0 & 15) * 2;
        bf16x8 af[4];
#pragma unroll
        for (int fm = 0; fm < 4; ++fm) {
            unsigned int dw = sxp[fm * 16 + lm][dwIdx];
            unsigned int c01 = (dw >> sh) & 0xFu;
            union { bf16x8 v; unsigned long long u[2]; } a;
            a.u[0] = 0x3F80ULL << ((c01 & 3u) * 16);   // j=0..3: one-hot c0
            a.u[1] = 0x3F80ULL << ((c01 >> 2) * 16);   // j=4..7: one-hot c1
            af[fm] = a.v;
        }

#pragma unroll
        for (int fm = 0; fm < 4; ++fm) {
            acc[fm][0] = __builtin_amdgcn_mfma_f32_16x16x32_bf16(af[fm], bh0, acc[fm][0], 0, 0, 0);
            acc[fm][0] = __builtin_amdgcn_mfma_f32_16x16x32_bf16(af[fm], bl0, acc[fm][0], 0, 0, 0);
            acc[fm][1] = __builtin_amdgcn_mfma_f32_16x16x32_bf16(af[fm], bh1, acc[fm][1], 0, 0, 0);
            acc[fm][1] = __builtin_amdgcn_mfma_f32_16x16x32_bf16(af[fm], bl1, acc[fm][1], 0, 0, 0);
        }
    }

    // epilogue: bias + relu + hi/lo split + store ([B][HID] row-major)
#pragma unroll
    for (int fm = 0; fm < 4; ++fm)
#pragma unroll
        for (int fn = 0; fn < 2; ++fn) {
            int n = n0 + wn + fn * 16 + lm;
            float bv = b1[n];
#pragma unroll
            for (int r = 0; r < 4; ++r) {
                int m = m0 + fm * 16 + kq * 4 + r;
                float v = fmaxf(acc[fm][fn][r] + bv, 0.f);
                unsigned short hi = f2bf_rne(v);
                float fhi = __uint_as_float((unsigned int)hi << 16);
                h_hi[(size_t)m * HID + n] = hi;
                h_lo[(size_t)m * HID + n] = f2bf_rne(v - fhi);
            }
        }
}

// ---------------------------------------------------------------------------
// f32 fallback hidden (small-workspace path)
// ---------------------------------------------------------------------------
__global__ __launch_bounds__(256) void k_hidden_f32(const int* __restrict__ x,
                                                    const float* __restrict__ W1,
                                                    const float* __restrict__ b1,
                                                    float* __restrict__ h) {
    int b = blockIdx.x, tid = threadIdx.x;
    __shared__ int sx[NORB];
    if (tid < NORB) sx[tid] = x[b * NORB + tid];
    __syncthreads();
    float acc[16];
#pragma unroll
    for (int u = 0; u < 16; ++u) acc[u] = b1[tid + 256 * u];
    for (int i = 0; i < NORB; ++i) {
        const float* row = W1 + (size_t)(4 * i + sx[i]) * HID;
#pragma unroll
        for (int u = 0; u < 16; ++u) acc[u] += row[tid + 256 * u];
    }
    float* hb = h + (size_t)b * HID;
#pragma unroll
    for (int u = 0; u < 16; ++u) hb[tid + 256 * u] = fmaxf(acc[u], 0.f);
}

// ---------------------------------------------------------------------------
// k_gemm3: corr = (h_hi+h_lo)@W2_hi + h_hi@W2_lo + b2 (unchanged, round 4).
// ---------------------------------------------------------------------------
#define GBM 64
#define GBN 128
#define LPAD 40

__global__ __launch_bounds__(256, 3) void k_gemm3(const unsigned short* __restrict__ Ah_g,
                                                  const unsigned short* __restrict__ Al_g,
                                                  const unsigned short* __restrict__ Bh_g,
                                                  const unsigned short* __restrict__ Bl_g,
                                                  const float* __restrict__ bias,
                                                  float* __restrict__ C) {
    __shared__ unsigned short Ah[GBM][LPAD], Al[GBM][LPAD];

    int n0 = blockIdx.x * GBN;
    int m0 = blockIdx.y * GBM;
    int t = threadIdx.x;
    int w = t >> 6, lane = t & 63;
    int lm = lane & 15, kq = lane >> 4;
    int wn = w * 32;

    int ma = t >> 2, ga = t & 3;
    const unsigned short* agh = Ah_g + (size_t)(m0 + ma) * HID + ga * 8;
    const unsigned short* agl = Al_g + (size_t)(m0 + ma) * HID + ga * 8;

    size_t nt0 = (size_t)((n0 + wn) >> 4);
    const unsigned short* bph = Bh_g + nt0 * 65536 + (size_t)lane * 8;
    const unsigned short* bpl = Bl_g + nt0 * 65536 + (size_t)lane * 8;

    f32x4 acc[4][2] = {};

    float4 vah = *(const float4*)(agh);
    float4 val = *(const float4*)(agl);

    for (int kt = 0; kt < 128; ++kt) {
        if (kt) __syncthreads();

        bf16x8 cbh0 = *(const bf16x8*)(bph + (size_t)kt * 512);
        bf16x8 cbh1 = *(const bf16x8*)(bph + 65536u + (size_t)kt * 512);
        bf16x8 cbl0 = *(const bf16x8*)(bpl + (size_t)kt * 512);
        bf16x8 cbl1 = *(const bf16x8*)(bpl + 65536u + (size_t)kt * 512);

        *(float4*)&Ah[ma][ga * 8] = vah;
        *(float4*)&Al[ma][ga * 8] = val;
        __syncthreads();

        if (kt + 1 < 128) {
            vah = *(const float4*)(agh + (kt + 1) * 32);
            val = *(const float4*)(agl + (kt + 1) * 32);
        }

        bf16x8 afh[4], afl[4];
#pragma unroll
        for (int fm = 0; fm < 4; ++fm) {
            afh[fm] = *(const bf16x8*)&Ah[fm * 16 + lm][kq * 8];
            afl[fm] = *(const bf16x8*)&Al[fm * 16 + lm][kq * 8];
        }

#pragma unroll
        for (int fm = 0; fm < 4; ++fm) {
            acc[fm][0] = __builtin_amdgcn_mfma_f32_16x16x32_bf16(afh[fm], cbh0, acc[fm][0], 0, 0, 0);
            acc[fm][0] = __builtin_amdgcn_mfma_f32_16x16x32_bf16(afl[fm], cbh0, acc[fm][0], 0, 0, 0);
            acc[fm][0] = __builtin_amdgcn_mfma_f32_16x16x32_bf16(afh[fm], cbl0, acc[fm][0], 0, 0, 0);
            acc[fm][1] = __builtin_amdgcn_mfma_f32_16x16x32_bf16(afh[fm], cbh1, acc[fm][1], 0, 0, 0);
            acc[fm][1] = __builtin_amdgcn_mfma_f32_16x16x32_bf16(afl[fm], cbh1, acc[fm][1], 0, 0, 0);
            acc[fm][1] = __builtin_amdgcn_mfma_f32_16x16x32_bf16(afh[fm], cbl1, acc[fm][1], 0, 0, 0);
        }
    }

#pragma unroll
    for (int fm = 0; fm < 4; ++fm)
#pragma unroll
        for (int fn = 0; fn < 2; ++fn) {
            int n = n0 + wn + fn * 16 + lm;
            float bv = bias[n];
#pragma unroll
            for (int r = 0; r < 4; ++r) {
                int m = m0 + fm * 16 + kq * 4 + r;
                C[(size_t)m * NCORR + n] = acc[fm][fn][r] + bv;
            }
        }
}

// ---------------------------------------------------------------------------
// f32 fallback GEMM (round-2 kernel, unchanged)
// ---------------------------------------------------------------------------
#define BM 64
#define BN 64
#define BK 32
__global__ __launch_bounds__(256) void k_gemm(const float* __restrict__ A,
                                              const float* __restrict__ Bm,
                                              const float* __restrict__ bias,
                                              float* __restrict__ C) {
    __shared__ float As[BK][68];
    __shared__ float Bs[BK][BN];
    int n0 = blockIdx.x * BN, m0 = blockIdx.y * BM;
    int tid = threadIdx.x;
    int tm = tid >> 4, tn = tid & 15;
    int am = tid >> 3, ak = (tid & 7) * 4;
    int bk = tid >> 4, bn = (tid & 15) * 4;
    float acc[4][4] = {};
    for (int k0 = 0; k0 < HID; k0 += BK) {
#pragma unroll
        for (int s = 0; s < 2; ++s) {
            int m = am + 32 * s;
            float4 v = *(const float4*)(A + (size_t)(m0 + m) * HID + k0 + ak);
            As[ak + 0][m] = v.x; As[ak + 1][m] = v.y;
            As[ak + 2][m] = v.z; As[ak + 3][m] = v.w;
        }
#pragma unroll
        for (int s = 0; s < 2; ++s) {
            int k = bk + 16 * s;
            float4 v = *(const float4*)(Bm + (size_t)(k0 + k) * NCORR + n0 + bn);
            *(float4*)&Bs[k][bn] = v;
        }
        __syncthreads();
#pragma unroll
        for (int kk = 0; kk < BK; ++kk) {
            float4 a = *(const float4*)&As[kk][tm * 4];
            float4 bv = *(const float4*)&Bs[kk][tn * 4];
            float av[4] = {a.x, a.y, a.z, a.w};
            float bb[4] = {bv.x, bv.y, bv.z, bv.w};
#pragma unroll
            for (int i = 0; i < 4; ++i)
#pragma unroll
                for (int j = 0; j < 4; ++j) acc[i][j] += av[i] * bb[j];
        }
        __syncthreads();
    }
#pragma unroll
    for (int i = 0; i < 4; ++i) {
        int m = m0 + tm * 4 + i;
        float4 o;
        o.x = acc[i][0] + bias[n0 + tn * 4 + 0];
        o.y = acc[i][1] + bias[n0 + tn * 4 + 1];
        o.z = acc[i][2] + bias[n0 + tn * 4 + 2];
        o.w = acc[i][3] + bias[n0 + tn * 4 + 3];
        *(float4*)(C + (size_t)m * NCORR + n0 + tn * 4) = o;
    }
}

// ---------------------------------------------------------------------------
// Kernel C: gather + 32x32 LU (partial pivoting) per spin, planar complex out.
// ---------------------------------------------------------------------------
__global__ __launch_bounds__(128) void k_det(const int* __restrict__ x,
                                             const float* __restrict__ orbitals,
                                             const float* __restrict__ corr,
                                             float* __restrict__ out,
                                             int imag_off) {
    int b = blockIdx.x, tid = threadIdx.x;
    __shared__ int sx[NORB];
    __shared__ int yup[NUP], ydn[NUP];
    __shared__ float M[2][NUP][NUP + 1];
    __shared__ float rlog[2];
    __shared__ int rneg[2];

    sx[tid] = x[b * NORB + tid];
    __syncthreads();

    int occ = sx[tid];
    if (occ & 1) {
        int r = 0;
        for (int i = 0; i < tid; ++i) r += sx[i] & 1;
        yup[r] = tid;
    }
    if (occ & 2) {
        int r = 0;
        for (int i = 0; i < tid; ++i) r += (sx[i] >> 1) & 1;
        ydn[r] = tid;
    }
    __syncthreads();

    const float* cb = corr + (size_t)b * NCORR;
    for (int idx = tid; idx < 2 * NUP * NUP; idx += 128) {
        int s = idx >> 10;
        int i = (idx >> 5) & 31;
        int j = idx & 31;
        int r = s ? ydn[i] : yup[i];
        M[s][i][j] = orbitals[r * NUP + j] + cb[r * NUP + j];
    }
    __syncthreads();

    int wv = tid >> 6, lane = tid & 63;
    float (*Mm)[NUP + 1] = M[wv];
    float logdet = 0.f;
    int neg = 0;

    for (int k = 0; k < NUP; ++k) {
        float v = (lane >= k && lane < NUP) ? fabsf(Mm[lane][k]) : -1.f;
        int pi = lane;
#pragma unroll
        for (int off = 32; off > 0; off >>= 1) {
            float v2 = __shfl_down(v, off);
            int p2 = __shfl_down(pi, off);
            if (v2 > v) { v = v2; pi = p2; }
        }
        int p = __shfl(pi, 0);

        if (p != k) {
            if (lane < NUP) {
                float t1 = Mm[k][lane];
                Mm[k][lane] = Mm[p][lane];
                Mm[p][lane] = t1;
            }
            neg ^= 1;
        }
        __syncthreads();

        float pv = Mm[k][k];
        logdet += logf(fabsf(pv));
        if (pv < 0.f) neg ^= 1;

        int row = k + 1 + (lane & 31);
        int half = lane >> 5;
        if (row < NUP) {
            float f = Mm[row][k] / pv;
            for (int j = k + 1 + half; j < NUP; j += 2)
                Mm[row][j] -= f * Mm[k][j];
        }
        __syncthreads();
    }

    if (lane == 0) { rlog[wv] = logdet; rneg[wv] = neg; }
    __syncthreads();
    if (tid == 0) {
        out[b] = rlog[0] + rlog[1];
        if (imag_off > 0)
            out[imag_off + b] =
                (rneg[0] ^ rneg[1]) ? 3.14159265358979323846f : 0.f;
    }
}

// ---------------------------------------------------------------------------
extern "C" void kernel_launch(void* const* d_in, const int* in_sizes, int n_in,
                              void* d_out, int out_size, void* d_ws, size_t ws_size,
                              hipStream_t stream) {
    const int*   x        = (const int*)d_in[0];
    const float* orbitals = (const float*)d_in[1];
    const float* W1       = (const float*)d_in[2];
    const float* b1       = (const float*)d_in[3];
    const float* W2       = (const float*)d_in[4];
    const float* b2       = (const float*)d_in[5];
    float* out = (float*)d_out;
    int imag_off = (out_size == 2 * B_SZ) ? B_SZ : 0;

    const size_t need = (size_t)96 * 1024 * 1024;
    if (ws_size >= need) {
        unsigned short* h_hi = (unsigned short*)d_ws;                    //  8 MB
        unsigned short* h_lo = h_hi + (size_t)B_SZ * HID;                //  8 MB
        unsigned short* Bph  = h_lo + (size_t)B_SZ * HID;                // 32 MB
        unsigned short* Bpl  = Bph + (size_t)HID * NCORR;                // 32 MB
        float*          corr = (float*)(Bpl + (size_t)HID * NCORR);     // 16 MB

        // W1-pack + packed-x live INSIDE the corr buffer (consumed by
        // k_hidden2 before k_gemm3 writes corr).
        unsigned short* W1ph = (unsigned short*)corr;                    // 4 MB
        unsigned short* W1pl = W1ph + (size_t)K1 * HID;                  // 4 MB
        unsigned int*   xp   = (unsigned int*)(W1pl + (size_t)K1 * HID); // 32 KB

        k_packx<<<B_SZ / 32, 256, 0, stream>>>(x, xp);
        k_splitW<<<dim3(HID / 32, K1 / 64), 256, 0, stream>>>(W1, W1ph, W1pl, 16);
        k_splitW<<<dim3(NCORR / 32, HID / 64), 256, 0, stream>>>(W2, Bph, Bpl, 128);

        k_hidden2<<<dim3(HID / 128, B_SZ / 64), 256, 0, stream>>>(xp, W1ph, W1pl, b1, h_hi, h_lo);

        dim3 g2(NCORR / GBN, B_SZ / GBM);   // 32 x 16 = 512 blocks
        k_gemm3<<<g2, 256, 0, stream>>>(h_hi, h_lo, Bph, Bpl, b2, corr);
        k_det<<<B_SZ, 128, 0, stream>>>(x, orbitals, corr, out, imag_off);
    } else {
        float* h    = (float*)d_ws;
        float* corr = h + (size_t)B_SZ * HID;
        k_hidden_f32<<<B_SZ, 256, 0, stream>>>(x, W1, b1, h);
        dim3 g2(NCORR / BN, B_SZ / BM);
        k_gemm<<<g2, 256, 0, stream>>>(h, W2, b2, corr);
        k_det<<<B_SZ, 128, 0, stream>>>(x, orbitals, corr, out, imag_off);
    }
}